// Round 7
// baseline (280.011 us; speedup 1.0000x reference)
//
#include <hip/hip_runtime.h>

#define NTOK 4096          // N
#define BNROWS 8192        // B*N
#define EDIM 128
#define FDIM 512

typedef __attribute__((ext_vector_type(8))) short bf16x8;
typedef __attribute__((ext_vector_type(4))) float f32x4;

__device__ __forceinline__ ushort f2bf(float x) {
    union { float f; unsigned u; } c; c.f = x;
    unsigned r = c.u + 0x7FFF + ((c.u >> 16) & 1);
    return (ushort)(r >> 16);
}

// ---------------------------------------------------------------------------
// qkv_k: blocks [0,256): rows M0..M0+31:
//   rmsnorm(input1,ln1) -> A(bf16, LDS); stage Wq/Wk/Wv fp32->bf16 -> LDS;
//   3 GEMMs; epilogue: sigq = sigmoid(q) fp32; Mt[b][e][i]=exp(k)*v,
//   Mt[b][128+e][i]=exp(k) (bf16, i-contiguous).
// blocks [256,400): convert Wcomb/W1/W2 -> Wbf (Wcomb@0 W1@16384 W2@81920).
// ---------------------------------------------------------------------------
__launch_bounds__(256, 1)
__global__ void qkv_k(const float* __restrict__ input1, const float* __restrict__ ln1w,
                      const float* __restrict__ Wq, const float* __restrict__ Wk,
                      const float* __restrict__ Wv, const float* __restrict__ Wc,
                      const float* __restrict__ W1, const float* __restrict__ W2,
                      ushort* __restrict__ Wbf, float* __restrict__ sigq,
                      ushort* __restrict__ Mt) {
    const int bx = blockIdx.x, t = threadIdx.x;
    if (bx >= 256) {
        int off = (bx - 256) * 1024 + t * 4;
        const float* src; int o2;
        if (off < 16384)      { src = Wc; o2 = off; }
        else if (off < 81920) { src = W1; o2 = off - 16384; }
        else                  { src = W2; o2 = off - 81920; }
        float4 f = *(const float4*)(src + o2);
        ushort4 u; u.x = f2bf(f.x); u.y = f2bf(f.y); u.z = f2bf(f.z); u.w = f2bf(f.w);
        *(ushort4*)(Wbf + off) = u;
        return;
    }
    __shared__ ushort As[32 * 136];
    __shared__ ushort Bs[3][128 * 136];
    const int lane = t & 63, wv = t >> 6;
    const int m15 = lane & 15, quad = lane >> 4, kq = quad * 8;
    const int M0 = bx * 32;

    // A: rmsnorm rows (8 threads per row, shuffle-reduce width 8)
    {
        const int ar = t >> 3, c0 = (t & 7) * 16;
        const float* xr = input1 + (size_t)(M0 + ar) * EDIM + c0;
        float4 x[4];
        float ss = 0.f;
#pragma unroll
        for (int i = 0; i < 4; ++i) {
            x[i] = ((const float4*)xr)[i];
            ss += x[i].x * x[i].x + x[i].y * x[i].y + x[i].z * x[i].z + x[i].w * x[i].w;
        }
        ss += __shfl_down(ss, 4, 8);
        ss += __shfl_down(ss, 2, 8);
        ss += __shfl_down(ss, 1, 8);
        ss = __shfl(ss, 0, 8);
        float rr = rsqrtf(ss * (1.0f / 128.0f) + 1e-6f);
#pragma unroll
        for (int i = 0; i < 4; ++i) {
            float4 wv4 = *(const float4*)&ln1w[c0 + i * 4];
            ushort4 o;
            o.x = f2bf(x[i].x * rr * wv4.x);
            o.y = f2bf(x[i].y * rr * wv4.y);
            o.z = f2bf(x[i].z * rr * wv4.z);
            o.w = f2bf(x[i].w * rr * wv4.w);
            *(ushort4*)&As[ar * 136 + c0 + i * 4] = o;
        }
    }
    // B: three weight matrices fp32 -> bf16 inline
    {
        const int br = t >> 1, half = (t & 1) * 64;
        const float* srcs[3] = {Wq, Wk, Wv};
#pragma unroll
        for (int m = 0; m < 3; ++m) {
            const float* wsrc = srcs[m] + (size_t)br * 128 + half;
#pragma unroll
            for (int j = 0; j < 8; ++j) {
                float4 f0 = *(const float4*)(wsrc + j * 8);
                float4 f1 = *(const float4*)(wsrc + j * 8 + 4);
                bf16x8 u;
                u[0] = (short)f2bf(f0.x); u[1] = (short)f2bf(f0.y);
                u[2] = (short)f2bf(f0.z); u[3] = (short)f2bf(f0.w);
                u[4] = (short)f2bf(f1.x); u[5] = (short)f2bf(f1.y);
                u[6] = (short)f2bf(f1.z); u[7] = (short)f2bf(f1.w);
                *(bf16x8*)&Bs[m][br * 136 + half + j * 8] = u;
            }
        }
    }
    __syncthreads();

    f32x4 aq[2][2] = {}, ak[2][2] = {}, av[2][2] = {};
    const int c0w = wv * 32;
#pragma unroll
    for (int kc = 0; kc < 4; ++kc) {
        int ko = kc * 32 + kq;
        bf16x8 a0 = *(const bf16x8*)&As[m15 * 136 + ko];
        bf16x8 a1 = *(const bf16x8*)&As[(16 + m15) * 136 + ko];
#pragma unroll
        for (int ni = 0; ni < 2; ++ni) {
            int brow = (c0w + ni * 16 + m15) * 136 + ko;
            bf16x8 bq = *(const bf16x8*)&Bs[0][brow];
            bf16x8 bk = *(const bf16x8*)&Bs[1][brow];
            bf16x8 bv = *(const bf16x8*)&Bs[2][brow];
            aq[0][ni] = __builtin_amdgcn_mfma_f32_16x16x32_bf16(a0, bq, aq[0][ni], 0, 0, 0);
            aq[1][ni] = __builtin_amdgcn_mfma_f32_16x16x32_bf16(a1, bq, aq[1][ni], 0, 0, 0);
            ak[0][ni] = __builtin_amdgcn_mfma_f32_16x16x32_bf16(a0, bk, ak[0][ni], 0, 0, 0);
            ak[1][ni] = __builtin_amdgcn_mfma_f32_16x16x32_bf16(a1, bk, ak[1][ni], 0, 0, 0);
            av[0][ni] = __builtin_amdgcn_mfma_f32_16x16x32_bf16(a0, bv, av[0][ni], 0, 0, 0);
            av[1][ni] = __builtin_amdgcn_mfma_f32_16x16x32_bf16(a1, bv, av[1][ni], 0, 0, 0);
        }
    }
    const int b  = M0 >> 12;
    const int i0 = M0 & (NTOK - 1);
#pragma unroll
    for (int mi = 0; mi < 2; ++mi)
#pragma unroll
        for (int ni = 0; ni < 2; ++ni) {
            int e  = c0w + ni * 16 + m15;
            int ib = i0 + mi * 16 + quad * 4;
#pragma unroll
            for (int r = 0; r < 4; ++r)
                sigq[(size_t)(M0 + mi * 16 + quad * 4 + r) * EDIM + e] =
                    1.0f / (1.0f + __expf(-aq[mi][ni][r]));
            ushort4 pv, pk;
            float k0 = __expf(ak[mi][ni][0]); pv.x = f2bf(k0 * av[mi][ni][0]); pk.x = f2bf(k0);
            float k1 = __expf(ak[mi][ni][1]); pv.y = f2bf(k1 * av[mi][ni][1]); pk.y = f2bf(k1);
            float k2 = __expf(ak[mi][ni][2]); pv.z = f2bf(k2 * av[mi][ni][2]); pk.z = f2bf(k2);
            float k3 = __expf(ak[mi][ni][3]); pv.w = f2bf(k3 * av[mi][ni][3]); pk.w = f2bf(k3);
            *(ushort4*)&Mt[((size_t)b * 256 + e) * NTOK + ib]       = pv;
            *(ushort4*)&Mt[((size_t)b * 256 + 128 + e) * NTOK + ib] = pk;
        }
}

// ---------------------------------------------------------------------------
// Big GEMM: P[s][b][j][c] = sum_{i in K-range s} exp(coef*dis[b,j,i])*Mt[b,c,i]
// Tile 32j x 256c, BK=64, K-split 4 -> 1024 blocks, 3 blocks/CU.
// ---------------------------------------------------------------------------
__launch_bounds__(256, 3)
__global__ void big_gemm_k(const float* __restrict__ dis, const float* __restrict__ alphap,
                           const ushort* __restrict__ Mt, float* __restrict__ P) {
    __shared__ ushort As[32 * 72];
    __shared__ ushort Bs[256 * 72];
    const int t = threadIdx.x, lane = t & 63, wv = t >> 6;
    const int m15 = lane & 15, quad = lane >> 4, kq = quad * 8;
    const int j0 = blockIdx.x * 32;
    const int b  = blockIdx.y;
    const int s  = blockIdx.z;
    const float coef = -alphap[0] * 12.0f;   // log2(4096) = 12
    const float* disb = dis + (size_t)b * NTOK * NTOK;
    const ushort* Mtb = Mt + (size_t)b * 256 * NTOK;
    float* outp = P + ((size_t)(s * 2 + b) * NTOK + j0) * 256;

    f32x4 acc[2][4] = {};
    const int aj = t >> 3, ak = (t & 7) * 8;
    const int brow = t >> 3, bseg = (t & 7) * 8;
    const int k0 = s * (NTOK / 4);
    const int nIter = (NTOK / 4) / 64;   // 16

    float4 fa0, fa1;
    bf16x8 pb[8];
    {
        const float* ap = disb + (size_t)(j0 + aj) * NTOK + k0 + ak;
        fa0 = *(const float4*)ap; fa1 = *(const float4*)(ap + 4);
#pragma unroll
        for (int p = 0; p < 8; ++p)
            pb[p] = *(const bf16x8*)&Mtb[(size_t)(p * 32 + brow) * NTOK + k0 + bseg];
    }

    for (int it = 0; it < nIter; ++it) {
        bf16x8 a8;
        a8[0] = (short)f2bf(__expf(coef * fa0.x));
        a8[1] = (short)f2bf(__expf(coef * fa0.y));
        a8[2] = (short)f2bf(__expf(coef * fa0.z));
        a8[3] = (short)f2bf(__expf(coef * fa0.w));
        a8[4] = (short)f2bf(__expf(coef * fa1.x));
        a8[5] = (short)f2bf(__expf(coef * fa1.y));
        a8[6] = (short)f2bf(__expf(coef * fa1.z));
        a8[7] = (short)f2bf(__expf(coef * fa1.w));
        *(bf16x8*)&As[aj * 72 + ak] = a8;
#pragma unroll
        for (int p = 0; p < 8; ++p)
            *(bf16x8*)&Bs[(p * 32 + brow) * 72 + bseg] = pb[p];
        __syncthreads();
        if (it < nIter - 1) {
            int kn = k0 + (it + 1) * 64;
            const float* ap = disb + (size_t)(j0 + aj) * NTOK + kn + ak;
            fa0 = *(const float4*)ap; fa1 = *(const float4*)(ap + 4);
#pragma unroll
            for (int p = 0; p < 8; ++p)
                pb[p] = *(const bf16x8*)&Mtb[(size_t)(p * 32 + brow) * NTOK + kn + bseg];
        }
#pragma unroll
        for (int kh = 0; kh < 2; ++kh) {
            int ko = kh * 32 + kq;
            bf16x8 a0 = *(const bf16x8*)&As[m15 * 72 + ko];
            bf16x8 a1 = *(const bf16x8*)&As[(16 + m15) * 72 + ko];
#pragma unroll
            for (int ni = 0; ni < 4; ++ni) {
                bf16x8 bv = *(const bf16x8*)&Bs[(wv * 64 + ni * 16 + m15) * 72 + ko];
                acc[0][ni] = __builtin_amdgcn_mfma_f32_16x16x32_bf16(a0, bv, acc[0][ni], 0, 0, 0);
                acc[1][ni] = __builtin_amdgcn_mfma_f32_16x16x32_bf16(a1, bv, acc[1][ni], 0, 0, 0);
            }
        }
        __syncthreads();
    }
#pragma unroll
    for (int mi = 0; mi < 2; ++mi)
#pragma unroll
        for (int ni = 0; ni < 4; ++ni)
#pragma unroll
            for (int r = 0; r < 4; ++r) {
                int j = mi * 16 + quad * 4 + r;
                int c = wv * 64 + ni * 16 + m15;
                outp[(size_t)j * 256 + c] = acc[mi][ni][r];
            }
}

// ---------------------------------------------------------------------------
// Wcomb fused: A = attn = sigq*(sum P num / sum P den); GEMM x Wcomb(bf16);
// out1 = acc + input1 (LDS); d_out = out1 + b2; in-block rmsnorm -> h2 bf16.
// ---------------------------------------------------------------------------
__launch_bounds__(256, 2)
__global__ void wcomb_rms2_k(const float* __restrict__ sigq, const float* __restrict__ P,
                             const ushort* __restrict__ Wbf,
                             const float* __restrict__ input1, const float* __restrict__ b2,
                             const float* __restrict__ ln2w,
                             float* __restrict__ outD, ushort* __restrict__ h2) {
    __shared__ ushort As[32 * 136];
    __shared__ ushort Bs[128 * 136];
    __shared__ float  O[32][132];
    const int t = threadIdx.x, lane = t & 63, wv = t >> 6;
    const int m15 = lane & 15, quad = lane >> 4, kq = quad * 8;
    const int M0 = blockIdx.x * 32;

    {   // A staging: attn rows
        const int ar = t >> 3, e0 = (t & 7) * 16;
        const int g = M0 + ar;
        const int b = g >> 12, j = g & (NTOK - 1);
        const float* sg = sigq + (size_t)g * 128 + e0;
        const float* Pg0 = P + ((size_t)(0 + b) * NTOK + j) * 256 + e0;
        const float* Pg1 = P + ((size_t)(2 + b) * NTOK + j) * 256 + e0;
        const float* Pg2 = P + ((size_t)(4 + b) * NTOK + j) * 256 + e0;
        const float* Pg3 = P + ((size_t)(6 + b) * NTOK + j) * 256 + e0;
#pragma unroll
        for (int i = 0; i < 4; ++i) {
            float4 s = *(const float4*)(sg + i * 4);
            float4 n0 = *(const float4*)(Pg0 + i * 4);
            float4 n1 = *(const float4*)(Pg1 + i * 4);
            float4 n2 = *(const float4*)(Pg2 + i * 4);
            float4 n3 = *(const float4*)(Pg3 + i * 4);
            float4 d0 = *(const float4*)(Pg0 + 128 + i * 4);
            float4 d1 = *(const float4*)(Pg1 + 128 + i * 4);
            float4 d2 = *(const float4*)(Pg2 + 128 + i * 4);
            float4 d3 = *(const float4*)(Pg3 + 128 + i * 4);
            ushort4 a;
            a.x = f2bf(s.x * (n0.x + n1.x + n2.x + n3.x) / (d0.x + d1.x + d2.x + d3.x));
            a.y = f2bf(s.y * (n0.y + n1.y + n2.y + n3.y) / (d0.y + d1.y + d2.y + d3.y));
            a.z = f2bf(s.z * (n0.z + n1.z + n2.z + n3.z) / (d0.z + d1.z + d2.z + d3.z));
            a.w = f2bf(s.w * (n0.w + n1.w + n2.w + n3.w) / (d0.w + d1.w + d2.w + d3.w));
            *(ushort4*)&As[ar * 136 + e0 + i * 4] = a;
        }
    }
    {   // B staging: Wcomb bf16
        const int br = t >> 1, half = (t & 1) * 64;
#pragma unroll
        for (int j = 0; j < 8; ++j)
            *(bf16x8*)&Bs[br * 136 + half + j * 8] =
                *(const bf16x8*)&Wbf[(size_t)br * 128 + half + j * 8];
    }
    __syncthreads();

    f32x4 acc[2][2] = {};
    const int c0w = wv * 32;
#pragma unroll
    for (int kc = 0; kc < 4; ++kc) {
        int ko = kc * 32 + kq;
        bf16x8 a0 = *(const bf16x8*)&As[m15 * 136 + ko];
        bf16x8 a1 = *(const bf16x8*)&As[(16 + m15) * 136 + ko];
        bf16x8 b0 = *(const bf16x8*)&Bs[(c0w + m15) * 136 + ko];
        bf16x8 b1 = *(const bf16x8*)&Bs[(c0w + 16 + m15) * 136 + ko];
        acc[0][0] = __builtin_amdgcn_mfma_f32_16x16x32_bf16(a0, b0, acc[0][0], 0, 0, 0);
        acc[0][1] = __builtin_amdgcn_mfma_f32_16x16x32_bf16(a0, b1, acc[0][1], 0, 0, 0);
        acc[1][0] = __builtin_amdgcn_mfma_f32_16x16x32_bf16(a1, b0, acc[1][0], 0, 0, 0);
        acc[1][1] = __builtin_amdgcn_mfma_f32_16x16x32_bf16(a1, b1, acc[1][1], 0, 0, 0);
    }
#pragma unroll
    for (int mi = 0; mi < 2; ++mi)
#pragma unroll
        for (int ni = 0; ni < 2; ++ni)
#pragma unroll
            for (int r = 0; r < 4; ++r) {
                int rl = mi * 16 + quad * 4 + r;
                int col = c0w + ni * 16 + m15;
                size_t off = (size_t)(M0 + rl) * 128 + col;
                float v = acc[mi][ni][r] + input1[off];
                O[rl][col] = v;
                outD[off] = v + b2[col];
            }
    __syncthreads();
    {   // rmsnorm rows of O -> h2 bf16
        const int row = t >> 3, seg = t & 7;
        float4 x[4];
        float ss = 0.f;
#pragma unroll
        for (int i = 0; i < 4; ++i) {
            x[i] = *(const float4*)&O[row][seg * 16 + i * 4];
            ss += x[i].x * x[i].x + x[i].y * x[i].y + x[i].z * x[i].z + x[i].w * x[i].w;
        }
        ss += __shfl_down(ss, 4, 8);
        ss += __shfl_down(ss, 2, 8);
        ss += __shfl_down(ss, 1, 8);
        ss = __shfl(ss, 0, 8);
        float rr = rsqrtf(ss * (1.0f / 128.0f) + 1e-6f);
        ushort* hp = h2 + (size_t)(M0 + row) * 128 + seg * 16;
#pragma unroll
        for (int i = 0; i < 4; ++i) {
            float4 wv4 = *(const float4*)&ln2w[seg * 16 + i * 4];
            ushort4 o;
            o.x = f2bf(x[i].x * rr * wv4.x);
            o.y = f2bf(x[i].y * rr * wv4.y);
            o.z = f2bf(x[i].z * rr * wv4.z);
            o.w = f2bf(x[i].w * rr * wv4.w);
            *(ushort4*)&hp[i * 4] = o;
        }
    }
}

// ---------------------------------------------------------------------------
// ffn_k: fused FFN. mid[32][512] = relu(h2 @ W1^T + b1) lives in LDS (bf16),
// then out += mid @ W2^T. W1@Wbf+16384, W2@Wbf+81920.
// ---------------------------------------------------------------------------
__launch_bounds__(256, 2)
__global__ void ffn_k(const ushort* __restrict__ h2, const ushort* __restrict__ Wbf,
                      const float* __restrict__ b1, float* __restrict__ out) {
    __shared__ ushort As[32 * 136];
    __shared__ ushort Am[32 * 520];
    __shared__ ushort Bs[128 * 136];
    const int t = threadIdx.x, lane = t & 63, wv = t >> 6;
    const int m15 = lane & 15, quad = lane >> 4, kq = quad * 8;
    const int M0 = blockIdx.x * 32;
    const int c0w = wv * 32;
    const int br = t >> 1, half = (t & 1) * 64;
    const ushort* W1bf = Wbf + 16384;
    const ushort* W2bf = Wbf + 81920;

    {   // A staging: h2 rows
        const int ar = t >> 3, a0 = (t & 7) * 16;
        *(bf16x8*)&As[ar * 136 + a0]     = *(const bf16x8*)&h2[(size_t)(M0 + ar) * 128 + a0];
        *(bf16x8*)&As[ar * 136 + a0 + 8] = *(const bf16x8*)&h2[(size_t)(M0 + ar) * 128 + a0 + 8];
    }
    // phase 1: mid chunks
    for (int fc = 0; fc < 4; ++fc) {
        __syncthreads();
#pragma unroll
        for (int j = 0; j < 8; ++j)
            *(bf16x8*)&Bs[br * 136 + half + j * 8] =
                *(const bf16x8*)&W1bf[(size_t)(fc * 128 + br) * 128 + half + j * 8];
        __syncthreads();
        f32x4 acc[2][2] = {};
#pragma unroll
        for (int kc = 0; kc < 4; ++kc) {
            int ko = kc * 32 + kq;
            bf16x8 a0 = *(const bf16x8*)&As[m15 * 136 + ko];
            bf16x8 a1 = *(const bf16x8*)&As[(16 + m15) * 136 + ko];
            bf16x8 b0 = *(const bf16x8*)&Bs[(c0w + m15) * 136 + ko];
            bf16x8 b1v = *(const bf16x8*)&Bs[(c0w + 16 + m15) * 136 + ko];
            acc[0][0] = __builtin_amdgcn_mfma_f32_16x16x32_bf16(a0, b0, acc[0][0], 0, 0, 0);
            acc[0][1] = __builtin_amdgcn_mfma_f32_16x16x32_bf16(a0, b1v, acc[0][1], 0, 0, 0);
            acc[1][0] = __builtin_amdgcn_mfma_f32_16x16x32_bf16(a1, b0, acc[1][0], 0, 0, 0);
            acc[1][1] = __builtin_amdgcn_mfma_f32_16x16x32_bf16(a1, b1v, acc[1][1], 0, 0, 0);
        }
#pragma unroll
        for (int mi = 0; mi < 2; ++mi)
#pragma unroll
            for (int ni = 0; ni < 2; ++ni)
#pragma unroll
                for (int r = 0; r < 4; ++r) {
                    int row = mi * 16 + quad * 4 + r;
                    int col = c0w + ni * 16 + m15;
                    Am[row * 520 + fc * 128 + col] =
                        f2bf(fmaxf(acc[mi][ni][r] + b1[fc * 128 + col], 0.0f));
                }
    }
    // phase 2: out += mid @ W2^T
    f32x4 acc2[2][2] = {};
    for (int kc = 0; kc < 4; ++kc) {
        __syncthreads();
#pragma unroll
        for (int j = 0; j < 8; ++j)
            *(bf16x8*)&Bs[br * 136 + half + j * 8] =
                *(const bf16x8*)&W2bf[(size_t)br * 512 + kc * 128 + half + j * 8];
        __syncthreads();
#pragma unroll
        for (int kk = 0; kk < 4; ++kk) {
            int koA = kc * 128 + kk * 32 + kq;
            int koB = kk * 32 + kq;
            bf16x8 a0 = *(const bf16x8*)&Am[m15 * 520 + koA];
            bf16x8 a1 = *(const bf16x8*)&Am[(16 + m15) * 520 + koA];
            bf16x8 b0 = *(const bf16x8*)&Bs[(c0w + m15) * 136 + koB];
            bf16x8 b1v = *(const bf16x8*)&Bs[(c0w + 16 + m15) * 136 + koB];
            acc2[0][0] = __builtin_amdgcn_mfma_f32_16x16x32_bf16(a0, b0, acc2[0][0], 0, 0, 0);
            acc2[0][1] = __builtin_amdgcn_mfma_f32_16x16x32_bf16(a0, b1v, acc2[0][1], 0, 0, 0);
            acc2[1][0] = __builtin_amdgcn_mfma_f32_16x16x32_bf16(a1, b0, acc2[1][0], 0, 0, 0);
            acc2[1][1] = __builtin_amdgcn_mfma_f32_16x16x32_bf16(a1, b1v, acc2[1][1], 0, 0, 0);
        }
    }
#pragma unroll
    for (int mi = 0; mi < 2; ++mi)
#pragma unroll
        for (int ni = 0; ni < 2; ++ni)
#pragma unroll
            for (int r = 0; r < 4; ++r) {
                int row = M0 + mi * 16 + quad * 4 + r;
                int col = c0w + ni * 16 + m15;
                size_t off = (size_t)row * 128 + col;
                out[off] += acc2[mi][ni][r];
            }
}

// ---------------------------------------------------------------------------
extern "C" void kernel_launch(void* const* d_in, const int* in_sizes, int n_in,
                              void* d_out, int out_size, void* d_ws, size_t ws_size,
                              hipStream_t stream) {
    const float* input1 = (const float*)d_in[0];
    const float* dis    = (const float*)d_in[1];
    const float* Wq     = (const float*)d_in[2];
    const float* Wk     = (const float*)d_in[3];
    const float* Wv     = (const float*)d_in[4];
    const float* alpha  = (const float*)d_in[5];
    const float* ln1    = (const float*)d_in[6];
    const float* ln2    = (const float*)d_in[7];
    const float* Wcomb  = (const float*)d_in[8];
    const float* W1     = (const float*)d_in[9];
    const float* b1     = (const float*)d_in[10];
    const float* W2     = (const float*)d_in[11];
    const float* b2     = (const float*)d_in[12];
    float* out = (float*)d_out;

    char* w8 = (char*)d_ws;
    ushort* Wbf  = (ushort*)(w8);                  // [0, 288K)  Wcomb/W1/W2 bf16
    float*  sigq = (float*)(w8 + (4u << 20));      // [4,8M)
    ushort* Mt   = (ushort*)(w8 + (8u << 20));     // [8,12M)
    ushort* h2   = (ushort*)(w8 + (12u << 20));    // [12,14M)
    float*  P    = (float*)(w8 + (16u << 20));     // [16,49.6M) 4 K-splits

    // 1) rmsnorm1 + q/k/v GEMMs -> sigq, Mt; side-blocks convert Wcomb/W1/W2
    qkv_k<<<dim3(400), 256, 0, stream>>>(input1, ln1, Wq, Wk, Wv, Wcomb, W1, W2,
                                         Wbf, sigq, Mt);
    // 2) big GEMM, K-split 4
    big_gemm_k<<<dim3(128, 2, 4), 256, 0, stream>>>(dis, alpha, Mt, P);
    // 3) attn + Wcomb + residual + b2 + rmsnorm2
    wcomb_rms2_k<<<dim3(256), 256, 0, stream>>>(sigq, P, Wbf, input1, b2, ln2, out, h2);
    // 4) fused FFN: out += relu(h2 @ W1^T + b1) @ W2^T
    ffn_k<<<dim3(256), 256, 0, stream>>>(h2, Wbf, b1, out);
}